// Round 6
// baseline (6155.792 us; speedup 1.0000x reference)
//
#include <hip/hip_runtime.h>

// Problem constants (B,S,D,H = 64,512,1024,1024)
#define S_LEN 512
#define BATCH 64
#define HDIM  1024
#define GDIM  3072   // 3*H

typedef __attribute__((ext_vector_type(8))) short bf16x8;           // MFMA A/B frag (8 bf16)
typedef __attribute__((ext_vector_type(4))) float f32x4;            // MFMA C/D frag
typedef __attribute__((ext_vector_type(4))) unsigned short u16x4;   // 4 bf16

__device__ inline unsigned short f2bf(float f) {
  unsigned u = __builtin_bit_cast(unsigned, f);
  u += 0x7fffu + ((u >> 16) & 1u);          // RNE (inputs are normal floats)
  return (unsigned short)(u >> 16);
}
__device__ inline float bf2f(unsigned short h) {
  unsigned u = ((unsigned)h) << 16;
  return __builtin_bit_cast(float, u);
}
__device__ inline bf16x8 pack8(float4 a, float4 b) {
  bf16x8 r;
  r[0] = (short)f2bf(a.x); r[1] = (short)f2bf(a.y);
  r[2] = (short)f2bf(a.z); r[3] = (short)f2bf(a.w);
  r[4] = (short)f2bf(b.x); r[5] = (short)f2bf(b.y);
  r[6] = (short)f2bf(b.z); r[7] = (short)f2bf(b.w);
  return r;
}
__device__ inline bf16x8 pack8v(f32x4 a, f32x4 b) {
  bf16x8 r;
  r[0] = (short)f2bf(a[0]); r[1] = (short)f2bf(a[1]);
  r[2] = (short)f2bf(a[2]); r[3] = (short)f2bf(a[3]);
  r[4] = (short)f2bf(b[0]); r[5] = (short)f2bf(b[1]);
  r[6] = (short)f2bf(b[2]); r[7] = (short)f2bf(b[3]);
  return r;
}

// ---------------------------------------------------------------------------
// Phase 1: xg[s][g][b] = sum_d U[b][s][d] * Wih[g][d] + bih[g]   (bf16 out)
// (unchanged)
// ---------------------------------------------------------------------------
__global__ __launch_bounds__(256, 2) void xg_gemm(
    const float* __restrict__ U, const float* __restrict__ Wih,
    const float* __restrict__ bih, unsigned short* __restrict__ xg) {
  __shared__ bf16x8 Asub[512];   // 128 rows x 4 chunks (8KB)
  __shared__ bf16x8 Bsub[512];

  const int bid = blockIdx.x;
  const int nt = bid % 24;       // N-tile (gate cols) fastest: W_ih L2 reuse
  const int mt = bid / 24;
  const int tid = threadIdx.x;
  const int wave = tid >> 6, lane = tid & 63;
  const int q = lane >> 4, l15 = lane & 15;
  const int wm = wave >> 1, wn = wave & 1;

  const int srow = tid >> 1, shalf = tid & 1;
  const int arow = mt * 128 + srow;            // M index = s*64+b ordering
  const float* Ag = U + ((size_t)(arow & 63) * S_LEN + (arow >> 6)) * HDIM + shalf * 16;
  const float* Bg = Wih + (size_t)(nt * 128 + srow) * HDIM + shalf * 16;
  const int sw = (srow >> 1) & 3;
  const int slot0 = srow * 4 + ((shalf * 2) ^ sw);
  const int slot1 = srow * 4 + ((shalf * 2 + 1) ^ sw);

  f32x4 acc[4][4];
#pragma unroll
  for (int i = 0; i < 4; ++i)
#pragma unroll
    for (int j = 0; j < 4; ++j) acc[i][j] = (f32x4){0.f, 0.f, 0.f, 0.f};

  for (int kk = 0; kk < 32; ++kk) {
    const float4* ap = (const float4*)(Ag + kk * 32);
    float4 a0 = ap[0], a1 = ap[1], a2 = ap[2], a3 = ap[3];
    const float4* bp = (const float4*)(Bg + kk * 32);
    float4 b0 = bp[0], b1 = bp[1], b2 = bp[2], b3 = bp[3];
    Asub[slot0] = pack8(a0, a1);
    Asub[slot1] = pack8(a2, a3);
    Bsub[slot0] = pack8(b0, b1);
    Bsub[slot1] = pack8(b2, b3);
    __syncthreads();
    bf16x8 af[4], bfr[4];
#pragma unroll
    for (int i = 0; i < 4; ++i) {
      int ar = wm * 64 + i * 16 + l15;
      af[i] = Asub[ar * 4 + (q ^ ((ar >> 1) & 3))];
      int br = wn * 64 + i * 16 + l15;
      bfr[i] = Bsub[br * 4 + (q ^ ((br >> 1) & 3))];
    }
#pragma unroll
    for (int i = 0; i < 4; ++i)
#pragma unroll
      for (int j = 0; j < 4; ++j)
        acc[i][j] = __builtin_amdgcn_mfma_f32_16x16x32_bf16(af[i], bfr[j], acc[i][j], 0, 0, 0);
    __syncthreads();
  }

#pragma unroll
  for (int j = 0; j < 4; ++j) {
    int gcol = nt * 128 + wn * 64 + j * 16 + l15;
    float bias = bih[gcol];
#pragma unroll
    for (int i = 0; i < 4; ++i) {
      int rbase = mt * 128 + wm * 64 + i * 16 + q * 4;
      int s = rbase >> 6;
      int b0i = rbase & 63;
      u16x4 pk;
#pragma unroll
      for (int r = 0; r < 4; ++r) pk[r] = f2bf(acc[i][j][r] + bias);
      *(u16x4*)(xg + ((size_t)s * GDIM + gcol) * BATCH + b0i) = pk;
    }
  }
}

// ---------------------------------------------------------------------------
// Phase 2 (round-11): persistent GRU scan with IN-BAND TAGGED h exchange.
//
// Round-5 counter analysis: step = 5.45us, of which ~3.5us is the flag
// protocol's serialized MALL chain (h-store drain -> flag store -> poll
// detect -> h reload). Fix: tags travel WITH the data.
//
//  * h stored as fp32 with low 8 mantissa bits = (step & 0xff). Tag error
//    2^-15 relative — far below the bf16 rounding already applied at MFMA.
//  * Producers fire-and-forget (global_store_dwordx4 sc0 sc1, NO drain,
//    NO flag). Consumers' staging loads ARE the poll: 32 dwordx4 sc0 sc1
//    per wave, re-issued (per 8-load batch) until every word's tag byte
//    == t. Per-word tags make stale/torn reads individually detectable.
//  * Self-synchronizing skew bound: a block enters step t+1 only after
//    validating ALL of h^(t+1), which proves every producer finished step
//    t — and therefore finished READING h^t (stage precedes combine in
//    program order). So the opposite half of the double buffer is never
//    overwritten under a reader.
//  * vmcnt counting under retries is sound: vmem ops retire in issue
//    order (m135), so older outstanding ops only make vmcnt(N) stricter;
//    retry waits use vmcnt(0).
//  * 2 __syncthreads per step (LDS phases only); flag barrier gone.
//
// LDS/GEMM/combine structure verbatim from the passing round-5 kernel.
// Fallback: if ws_size can't hold the fp32 h buffer (512KB), launch the
// round-5 kernel unchanged (gru_scan_flags below).
// ---------------------------------------------------------------------------
__global__ __launch_bounds__(512, 1) void gru_scan_tag(
    const float* __restrict__ Whh, const float* __restrict__ bhh,
    const unsigned short* __restrict__ xg, float* __restrict__ hb32,
    float* __restrict__ out) {
  __shared__ unsigned short hls[8 * 8192];   // 128KB: 8 wave regions [64][128]
  __shared__ float bh_lds[3][16];

  const int p = blockIdx.x;
  const int j0 = p * 16;
  const int tid = threadIdx.x;
  const int w = tid >> 6, lane = tid & 63;
  const int q = lane >> 4, l15 = lane & 15;
  const int k0 = w * 128;            // wave's K-slice
  const int cb = tid >> 2;           // combine: batch row 0..63 (tid<256)
  const int cmq = (tid & 3) * 4;     // combine: m-quad 0,4,8,12

  // staging decomposition: lane covers rows srow0+4j (j=0..15), 8-col group sc
  const int srow0 = lane >> 4;       // 0..3
  const int sc = lane & 15;          // 8-fp32-col group within k-slice

  // A-frags resident in VGPRs: wf[g][kk] = Whh[g*1024+j0+l15][k0+kk*32+q*8..]
  bf16x8 wf[3][4];
#pragma unroll
  for (int g = 0; g < 3; ++g) {
    const float* wrow = Whh + ((size_t)g * HDIM + j0 + l15) * HDIM + k0;
#pragma unroll
    for (int kk = 0; kk < 4; ++kk) {
      const float4* wp = (const float4*)(wrow + kk * 32 + q * 8);
      wf[g][kk] = pack8(wp[0], wp[1]);
    }
  }
  if (tid < 48) bh_lds[tid >> 4][tid & 15] = bhh[(tid >> 4) * HDIM + j0 + (tid & 15)];
  __syncthreads();

  float4 hv = {0.f, 0.f, 0.f, 0.f};   // fp32 carry (tid<256: b=cb, m=cmq..+3)
  unsigned short xq[3][4];

// issue one 8-chunk batch (4 rows x 2 halves) of tagged-h loads
#define ISSUE8(V0, V1, V2, V3, V4, V5, V6, V7, P0, P1, P2, P3)            \
  asm volatile(                                                           \
      "global_load_dwordx4 %0, %8, off sc0 sc1\n\t"                       \
      "global_load_dwordx4 %1, %8, off offset:16 sc0 sc1\n\t"             \
      "global_load_dwordx4 %2, %9, off sc0 sc1\n\t"                       \
      "global_load_dwordx4 %3, %9, off offset:16 sc0 sc1\n\t"             \
      "global_load_dwordx4 %4, %10, off sc0 sc1\n\t"                      \
      "global_load_dwordx4 %5, %10, off offset:16 sc0 sc1\n\t"            \
      "global_load_dwordx4 %6, %11, off sc0 sc1\n\t"                      \
      "global_load_dwordx4 %7, %11, off offset:16 sc0 sc1"                \
      : "=&v"(V0), "=&v"(V1), "=&v"(V2), "=&v"(V3),                       \
        "=&v"(V4), "=&v"(V5), "=&v"(V6), "=&v"(V7)                        \
      : "v"(P0), "v"(P1), "v"(P2), "v"(P3))

#define CHK(V)                                                            \
  {                                                                       \
    unsigned x0 = __builtin_bit_cast(unsigned, (V)[0]);                   \
    unsigned x1 = __builtin_bit_cast(unsigned, (V)[1]);                   \
    unsigned x2 = __builtin_bit_cast(unsigned, (V)[2]);                   \
    unsigned x3 = __builtin_bit_cast(unsigned, (V)[3]);                   \
    bad |= ((x0 ^ tg) | (x1 ^ tg) | (x2 ^ tg) | (x3 ^ tg)) & 0xffu;       \
  }

// validate batch; on stale data re-issue the batch and drain (retry is rare)
#define VAL8(V0, V1, V2, V3, V4, V5, V6, V7, P0, P1, P2, P3)              \
  {                                                                       \
    int rt = 0;                                                           \
    for (;;) {                                                            \
      unsigned bad = 0u;                                                  \
      CHK(V0) CHK(V1) CHK(V2) CHK(V3) CHK(V4) CHK(V5) CHK(V6) CHK(V7)     \
      if (!__any((int)bad)) break;                                        \
      if (++rt > 4096) break; /* visible wrong answer beats a hang */     \
      ISSUE8(V0, V1, V2, V3, V4, V5, V6, V7, P0, P1, P2, P3);             \
      asm volatile("s_waitcnt vmcnt(0)" ::: "memory");                    \
      __builtin_amdgcn_sched_barrier(0);                                  \
    }                                                                     \
  }

// pack validated fp32 pair -> bf16x8, store at G4-swizzled chunk slot
#define STW(J, VA, VB)                                                    \
  {                                                                       \
    const int row_ = srow0 + 4 * (J);                                     \
    const int c2_ = (sc & 8) | ((sc ^ row_) & 7);                         \
    *(bf16x8*)&hls[w * 8192 + row_ * 128 + c2_ * 8] = pack8v(VA, VB);     \
  }

  for (int t = 0; t < S_LEN; ++t) {
    const float* gb_t = hb32 + (size_t)(t & 1) * (BATCH * HDIM);
    float* gnx = hb32 + (size_t)((t + 1) & 1) * (BATCH * HDIM);
    const unsigned tg = (unsigned)(t & 0xff);

    // ---- stage+poll h[0:64][k0:k0+128): 32 tagged loads, all in flight ----
    {
      const float* pb = gb_t + (size_t)srow0 * HDIM + k0 + sc * 8;
      const float *pA0 = pb,               *pA1 = pb + 4 * HDIM,
                  *pA2 = pb + 8 * HDIM,    *pA3 = pb + 12 * HDIM,
                  *pB0 = pb + 16 * HDIM,   *pB1 = pb + 20 * HDIM,
                  *pB2 = pb + 24 * HDIM,   *pB3 = pb + 28 * HDIM,
                  *pC0 = pb + 32 * HDIM,   *pC1 = pb + 36 * HDIM,
                  *pC2 = pb + 40 * HDIM,   *pC3 = pb + 44 * HDIM,
                  *pD0 = pb + 48 * HDIM,   *pD1 = pb + 52 * HDIM,
                  *pD2 = pb + 56 * HDIM,   *pD3 = pb + 60 * HDIM;
      f32x4 a0, a1, a2, a3, a4, a5, a6, a7;
      f32x4 b0, b1, b2, b3, b4, b5, b6, b7;
      f32x4 c0, c1, c2, c3, c4, c5, c6, c7;
      f32x4 d0, d1, d2, d3, d4, d5, d6, d7;
      ISSUE8(a0, a1, a2, a3, a4, a5, a6, a7, pA0, pA1, pA2, pA3);
      ISSUE8(b0, b1, b2, b3, b4, b5, b6, b7, pB0, pB1, pB2, pB3);
      ISSUE8(c0, c1, c2, c3, c4, c5, c6, c7, pC0, pC1, pC2, pC3);
      ISSUE8(d0, d1, d2, d3, d4, d5, d6, d7, pD0, pD1, pD2, pD3);

      asm volatile("s_waitcnt vmcnt(24)" ::: "memory");
      __builtin_amdgcn_sched_barrier(0);
      VAL8(a0, a1, a2, a3, a4, a5, a6, a7, pA0, pA1, pA2, pA3);
      STW(0, a0, a1) STW(1, a2, a3) STW(2, a4, a5) STW(3, a6, a7)

      asm volatile("s_waitcnt vmcnt(16)" ::: "memory");
      __builtin_amdgcn_sched_barrier(0);
      VAL8(b0, b1, b2, b3, b4, b5, b6, b7, pB0, pB1, pB2, pB3);
      STW(4, b0, b1) STW(5, b2, b3) STW(6, b4, b5) STW(7, b6, b7)

      asm volatile("s_waitcnt vmcnt(8)" ::: "memory");
      __builtin_amdgcn_sched_barrier(0);
      VAL8(c0, c1, c2, c3, c4, c5, c6, c7, pC0, pC1, pC2, pC3);
      STW(8, c0, c1) STW(9, c2, c3) STW(10, c4, c5) STW(11, c6, c7)

      asm volatile("s_waitcnt vmcnt(0)" ::: "memory");
      __builtin_amdgcn_sched_barrier(0);
      VAL8(d0, d1, d2, d3, d4, d5, d6, d7, pD0, pD1, pD2, pD3);
      STW(12, d0, d1) STW(13, d2, d3) STW(14, d4, d5) STW(15, d6, d7)
    }

    // xg for this step (combine waves only; latency hides under GEMM)
    if (tid < 256) {
#pragma unroll
      for (int g = 0; g < 3; ++g)
#pragma unroll
        for (int r = 0; r < 4; ++r)
          xq[g][r] = xg[((size_t)t * GDIM + g * HDIM + j0 + cmq + r) * BATCH + cb];
    }

    // ---- GEMM phase: wave-private region, swizzled conflict-free reads ----
    f32x4 acc[3][4];
#pragma unroll
    for (int g = 0; g < 3; ++g)
#pragma unroll
      for (int bt = 0; bt < 4; ++bt) acc[g][bt] = (f32x4){0.f, 0.f, 0.f, 0.f};

#pragma unroll
    for (int kk = 0; kk < 4; ++kk) {
      const int c = kk * 4 + q;
      bf16x8 hB[4];
#pragma unroll
      for (int bt = 0; bt < 4; ++bt) {
        const int row = bt * 16 + l15;
        const int c2 = (c & 8) | ((c ^ row) & 7);
        hB[bt] = *(const bf16x8*)&hls[w * 8192 + row * 128 + c2 * 8];
      }
#pragma unroll
      for (int g = 0; g < 3; ++g) {
        acc[g][0] = __builtin_amdgcn_mfma_f32_16x16x32_bf16(wf[g][kk], hB[0], acc[g][0], 0, 0, 0);
        acc[g][1] = __builtin_amdgcn_mfma_f32_16x16x32_bf16(wf[g][kk], hB[1], acc[g][1], 0, 0, 0);
        acc[g][2] = __builtin_amdgcn_mfma_f32_16x16x32_bf16(wf[g][kk], hB[2], acc[g][2], 0, 0, 0);
        acc[g][3] = __builtin_amdgcn_mfma_f32_16x16x32_bf16(wf[g][kk], hB[3], acc[g][3], 0, 0, 0);
      }
    }
    __builtin_amdgcn_sched_barrier(0);

    // partials aliased into wave w's own region (all region reads feed accs)
    {
      float* pw = (float*)&hls[w * 8192];
      asm volatile("" : "+v"(pw));   // opaque: may alias anything
#pragma unroll
      for (int g = 0; g < 3; ++g)
#pragma unroll
        for (int bt = 0; bt < 4; ++bt)
#pragma unroll
          for (int r = 0; r < 4; ++r)
            pw[(g * 16 + q * 4 + r) * 66 + bt * 16 + l15] = acc[g][bt][r];
    }
    __syncthreads();

    // ---- combine: thread owns (b=cb, m in [cmq,cmq+4)) ----
    if (tid < 256) {
      float hnv[4];
#pragma unroll
      for (int r = 0; r < 4; ++r) {
        int m = cmq + r;
        float hr = bh_lds[0][m], hz = bh_lds[1][m], hn = bh_lds[2][m];
#pragma unroll
        for (int ww = 0; ww < 8; ++ww) {
          const float* pp = (const float*)&hls[ww * 8192];
          hr += pp[( 0 + m) * 66 + cb];
          hz += pp[(16 + m) * 66 + cb];
          hn += pp[(32 + m) * 66 + cb];
        }
        float xr = bf2f(xq[0][r]), xz = bf2f(xq[1][r]), xn = bf2f(xq[2][r]);
        float rr = 1.f / (1.f + __expf(-(xr + hr)));
        float zz = 1.f / (1.f + __expf(-(xz + hz)));
        float ex = __expf(2.f * (xn + rr * hn));
        float nn = 1.f - 2.f / (ex + 1.f);       // tanh
        float hold = (r == 0) ? hv.x : (r == 1) ? hv.y : (r == 2) ? hv.z : hv.w;
        float hnew = (1.f - zz) * nn + zz * hold;
        if (r == 0) hv.x = hnew; else if (r == 1) hv.y = hnew; else if (r == 2) hv.z = hnew; else hv.w = hnew;
        hnv[r] = hnew;
      }
      if (t + 1 < S_LEN) {
        // tagged fp32 store, fire-and-forget (tag rides with the data)
        const unsigned tgn = (unsigned)((t + 1) & 0xff);
        f32x4 st;
#pragma unroll
        for (int r = 0; r < 4; ++r) {
          unsigned u = (__builtin_bit_cast(unsigned, hnv[r]) & 0xffffff00u) | tgn;
          st[r] = __builtin_bit_cast(float, u);
        }
        const float* pst = gnx + (size_t)cb * HDIM + j0 + cmq;
        asm volatile("global_store_dwordx4 %0, %1, off sc0 sc1"
                     :: "v"(pst), "v"(st) : "memory");
      }
    }
    __syncthreads();   // LDS partials consumed; safe for next staging
  }

#undef ISSUE8
#undef CHK
#undef VAL8
#undef STW

  // final h -> out[b][j]  (fp32, float4, untagged carry)
  if (tid < 256)
    *(float4*)(out + (size_t)cb * HDIM + j0 + cmq) = hv;
}

// ---------------------------------------------------------------------------
// Fallback: round-5 kernel VERBATIM (proven: 2790us) for small workspaces.
// ---------------------------------------------------------------------------
__global__ __launch_bounds__(512, 1) void gru_scan_flags(
    const float* __restrict__ Whh, const float* __restrict__ bhh,
    const unsigned short* __restrict__ xg, unsigned short* __restrict__ hbuf,
    unsigned int* __restrict__ flags, float* __restrict__ out) {
  __shared__ unsigned short hls[8 * 8192];
  __shared__ float bh_lds[3][16];

  const int p = blockIdx.x;
  const int j0 = p * 16;
  const int tid = threadIdx.x;
  const int w = tid >> 6, lane = tid & 63;
  const int q = lane >> 4, l15 = lane & 15;
  const int k0 = w * 128;
  const int cb = tid >> 2;
  const int cmq = (tid & 3) * 4;
  const int srow0 = lane >> 4;
  const int sc = lane & 15;

  bf16x8 wf[3][4];
#pragma unroll
  for (int g = 0; g < 3; ++g) {
    const float* wrow = Whh + ((size_t)g * HDIM + j0 + l15) * HDIM + k0;
#pragma unroll
    for (int kk = 0; kk < 4; ++kk) {
      const float4* wp = (const float4*)(wrow + kk * 32 + q * 8);
      wf[g][kk] = pack8(wp[0], wp[1]);
    }
  }
  if (tid < 48) bh_lds[tid >> 4][tid & 15] = bhh[(tid >> 4) * HDIM + j0 + (tid & 15)];
  __syncthreads();

  float4 hv = {0.f, 0.f, 0.f, 0.f};
  unsigned short xq[3][4];
  if (tid < 256) {
#pragma unroll
    for (int g = 0; g < 3; ++g)
#pragma unroll
      for (int r = 0; r < 4; ++r)
        xq[g][r] = xg[((size_t)g * HDIM + j0 + cmq + r) * BATCH + cb];
  }

  const size_t HS = (size_t)BATCH * HDIM;
  int dead = 0;

  for (int t = 0; t < S_LEN; ++t) {
    const unsigned short* hcur = hbuf + (size_t)(t & 1) * HS;
    unsigned short* hnxt = hbuf + (size_t)((t + 1) & 1) * HS;
    {
      const unsigned short* gb = hcur + (size_t)srow0 * HDIM + k0 + sc * 8;
      const unsigned short *g0 = gb,            *g1 = gb + 4 * HDIM,
                           *g2 = gb + 8 * HDIM, *g3 = gb + 12 * HDIM,
                           *g4 = gb + 16 * HDIM,*g5 = gb + 20 * HDIM,
                           *g6 = gb + 24 * HDIM,*g7 = gb + 28 * HDIM;
      bf16x8 v0, v1, v2, v3, v4, v5, v6, v7;
      asm volatile(
          "global_load_dwordx4 %0, %8, off sc0 sc1\n\t"
          "global_load_dwordx4 %1, %9, off sc0 sc1\n\t"
          "global_load_dwordx4 %2, %10, off sc0 sc1\n\t"
          "global_load_dwordx4 %3, %11, off sc0 sc1\n\t"
          "global_load_dwordx4 %4, %12, off sc0 sc1\n\t"
          "global_load_dwordx4 %5, %13, off sc0 sc1\n\t"
          "global_load_dwordx4 %6, %14, off sc0 sc1\n\t"
          "global_load_dwordx4 %7, %15, off sc0 sc1"
          : "=&v"(v0), "=&v"(v1), "=&v"(v2), "=&v"(v3),
            "=&v"(v4), "=&v"(v5), "=&v"(v6), "=&v"(v7)
          : "v"(g0), "v"(g1), "v"(g2), "v"(g3),
            "v"(g4), "v"(g5), "v"(g6), "v"(g7));
      const unsigned short *g8 = gb + 32 * HDIM, *g9 = gb + 36 * HDIM,
                           *gA = gb + 40 * HDIM, *gB = gb + 44 * HDIM,
                           *gC = gb + 48 * HDIM, *gD = gb + 52 * HDIM,
                           *gE = gb + 56 * HDIM, *gF = gb + 60 * HDIM;
      bf16x8 v8, v9, vA, vB, vC, vD, vE, vF;
      asm volatile(
          "global_load_dwordx4 %0, %8, off sc0 sc1\n\t"
          "global_load_dwordx4 %1, %9, off sc0 sc1\n\t"
          "global_load_dwordx4 %2, %10, off sc0 sc1\n\t"
          "global_load_dwordx4 %3, %11, off sc0 sc1\n\t"
          "global_load_dwordx4 %4, %12, off sc0 sc1\n\t"
          "global_load_dwordx4 %5, %13, off sc0 sc1\n\t"
          "global_load_dwordx4 %6, %14, off sc0 sc1\n\t"
          "global_load_dwordx4 %7, %15, off sc0 sc1"
          : "=&v"(v8), "=&v"(v9), "=&v"(vA), "=&v"(vB),
            "=&v"(vC), "=&v"(vD), "=&v"(vE), "=&v"(vF)
          : "v"(g8), "v"(g9), "v"(gA), "v"(gB),
            "v"(gC), "v"(gD), "v"(gE), "v"(gF));

#define STWF(J, VV)                                                       \
      {                                                                   \
        const int row_ = srow0 + 4 * (J);                                 \
        const int c2_ = (sc & 8) | ((sc ^ row_) & 7);                     \
        *(bf16x8*)&hls[w * 8192 + row_ * 128 + c2_ * 8] = (VV);           \
      }
      asm volatile("s_waitcnt vmcnt(8)" ::: "memory");
      __builtin_amdgcn_sched_barrier(0);
      STWF(0, v0) STWF(1, v1) STWF(2, v2) STWF(3, v3)
      STWF(4, v4) STWF(5, v5) STWF(6, v6) STWF(7, v7)
      asm volatile("s_waitcnt vmcnt(0)" ::: "memory");
      __builtin_amdgcn_sched_barrier(0);
      STWF(8, v8) STWF(9, v9) STWF(10, vA) STWF(11, vB)
      STWF(12, vC) STWF(13, vD) STWF(14, vE) STWF(15, vF)
#undef STWF
    }

    f32x4 acc[3][4];
#pragma unroll
    for (int g = 0; g < 3; ++g)
#pragma unroll
      for (int bt = 0; bt < 4; ++bt) acc[g][bt] = (f32x4){0.f, 0.f, 0.f, 0.f};

#pragma unroll
    for (int kk = 0; kk < 4; ++kk) {
      const int c = kk * 4 + q;
      bf16x8 hB[4];
#pragma unroll
      for (int bt = 0; bt < 4; ++bt) {
        const int row = bt * 16 + l15;
        const int c2 = (c & 8) | ((c ^ row) & 7);
        hB[bt] = *(const bf16x8*)&hls[w * 8192 + row * 128 + c2 * 8];
      }
#pragma unroll
      for (int g = 0; g < 3; ++g) {
        acc[g][0] = __builtin_amdgcn_mfma_f32_16x16x32_bf16(wf[g][kk], hB[0], acc[g][0], 0, 0, 0);
        acc[g][1] = __builtin_amdgcn_mfma_f32_16x16x32_bf16(wf[g][kk], hB[1], acc[g][1], 0, 0, 0);
        acc[g][2] = __builtin_amdgcn_mfma_f32_16x16x32_bf16(wf[g][kk], hB[2], acc[g][2], 0, 0, 0);
        acc[g][3] = __builtin_amdgcn_mfma_f32_16x16x32_bf16(wf[g][kk], hB[3], acc[g][3], 0, 0, 0);
      }
    }
    __builtin_amdgcn_sched_barrier(0);

    {
      float* pw = (float*)&hls[w * 8192];
      asm volatile("" : "+v"(pw));
#pragma unroll
      for (int g = 0; g < 3; ++g)
#pragma unroll
        for (int bt = 0; bt < 4; ++bt)
#pragma unroll
          for (int r = 0; r < 4; ++r)
            pw[(g * 16 + q * 4 + r) * 66 + bt * 16 + l15] = acc[g][bt][r];
    }
    __syncthreads();

    if (tid < 256) {
      u16x4 pk;
#pragma unroll
      for (int r = 0; r < 4; ++r) {
        int m = cmq + r;
        float hr = bh_lds[0][m], hz = bh_lds[1][m], hn = bh_lds[2][m];
#pragma unroll
        for (int ww = 0; ww < 8; ++ww) {
          const float* pp = (const float*)&hls[ww * 8192];
          hr += pp[( 0 + m) * 66 + cb];
          hz += pp[(16 + m) * 66 + cb];
          hn += pp[(32 + m) * 66 + cb];
        }
        float xr = bf2f(xq[0][r]), xz = bf2f(xq[1][r]), xn = bf2f(xq[2][r]);
        float rr = 1.f / (1.f + __expf(-(xr + hr)));
        float zz = 1.f / (1.f + __expf(-(xz + hz)));
        float ex = __expf(2.f * (xn + rr * hn));
        float nn = 1.f - 2.f / (ex + 1.f);
        float hold = (r == 0) ? hv.x : (r == 1) ? hv.y : (r == 2) ? hv.z : hv.w;
        float hnew = (1.f - zz) * nn + zz * hold;
        if (r == 0) hv.x = hnew; else if (r == 1) hv.y = hnew; else if (r == 2) hv.z = hnew; else hv.w = hnew;
        pk[r] = f2bf(hnew);
      }
      if (t + 1 < S_LEN) {
        __hip_atomic_store((unsigned long long*)(hnxt + (size_t)cb * HDIM + j0 + cmq),
                           __builtin_bit_cast(unsigned long long, pk),
                           __ATOMIC_RELAXED, __HIP_MEMORY_SCOPE_AGENT);
      }
    }
    __syncthreads();

    if (t + 1 < S_LEN) {
      if (tid == 448)
        __hip_atomic_store(&flags[p], (unsigned)(t + 1),
                           __ATOMIC_RELAXED, __HIP_MEMORY_SCOPE_AGENT);
      if (tid < 256) {
#pragma unroll
        for (int g = 0; g < 3; ++g)
#pragma unroll
          for (int r = 0; r < 4; ++r)
            xq[g][r] = xg[((size_t)(t + 1) * GDIM + g * HDIM + j0 + cmq + r) * BATCH + cb];
      }
      if (tid >= 448 && !dead) {
        const unsigned int* fp = flags + (tid & 63);
        const unsigned want = (unsigned)(t + 1);
        unsigned spins = 0;
        while (__hip_atomic_load(fp, __ATOMIC_RELAXED, __HIP_MEMORY_SCOPE_AGENT)
               < want) {
          __builtin_amdgcn_s_sleep(1);
          if (++spins > 50000000u) { dead = 1; break; }
        }
      }
      __syncthreads();
    }
  }

  if (tid < 256)
    *(float4*)(out + (size_t)cb * HDIM + j0 + cmq) = hv;
}

// ---------------------------------------------------------------------------
extern "C" void kernel_launch(void* const* d_in, const int* in_sizes, int n_in,
                              void* d_out, int out_size, void* d_ws, size_t ws_size,
                              hipStream_t stream) {
  const float* U   = (const float*)d_in[0];
  const float* Wih = (const float*)d_in[1];
  const float* Whh = (const float*)d_in[2];
  const float* bih = (const float*)d_in[3];
  const float* bhh = (const float*)d_in[4];
  float* out = (float*)d_out;

  char* ws = (char*)d_ws;
  const size_t XG_BYTES = (size_t)S_LEN * GDIM * BATCH * 2;   // 201326592
  unsigned short* xg = (unsigned short*)ws;

  hipLaunchKernelGGL(xg_gemm, dim3((32768 / 128) * (GDIM / 128)), dim3(256), 0, stream,
                     U, Wih, bih, xg);

  const size_t H32_BYTES = (size_t)2 * BATCH * HDIM * 4;      // 524288 (fp32 dbuf)
  if (ws_size >= XG_BYTES + H32_BYTES) {
    // tagged protocol: fp32 h with in-band step tag; no flags
    float* hb32 = (float*)(ws + XG_BYTES);
    hipMemsetAsync(ws + XG_BYTES, 0, H32_BYTES, stream);      // h^0 = 0, tag 0
    hipLaunchKernelGGL(gru_scan_tag, dim3(64), dim3(512), 0, stream,
                       Whh, bhh, xg, hb32, out);
  } else {
    // fallback: round-5 proven protocol, known-safe footprint XG + 256K + 256
    unsigned short* hbuf = (unsigned short*)(ws + XG_BYTES);
    const size_t H_BYTES = (size_t)2 * BATCH * HDIM * 2;      // 262144
    unsigned int* flags = (unsigned int*)(ws + XG_BYTES + H_BYTES);
    hipMemsetAsync(ws + XG_BYTES, 0, H_BYTES + 256, stream);
    hipLaunchKernelGGL(gru_scan_flags, dim3(64), dim3(512), 0, stream,
                       Whh, bhh, xg, hbuf, flags, out);
  }
}